// Round 6
// baseline (1298.501 us; speedup 1.0000x reference)
//
#include <hip/hip_runtime.h>
#include <cfloat>

#define K_NUM 512
#define C_DIM 256
#define MAXTAB 8

// workspace float offsets — small fixed region first, replicated tables last
#define WS_CNT    0          // [512] cluster counts
#define WS_ESQ    512        // [512] ||e_k||^2
#define WS_SMOOTH 1024       // [512] smoothed cluster size
#define WS_LOSS   1536       // [1] (+pad)
#define WS_CBT    2048       // [256][512] transposed codebook
#define WS_ACC    133120     // ntab x [512][256] embed-sum accumulators

// output float offsets (z_q, vq_loss, indices, new_codebook, new_cluster_size, new_embed_sum)
#define OFF_LOSS 16777216
#define OFF_IDX  16777217
#define OFF_CB   16842753
#define OFF_CS   16973825
#define OFF_ES   16974337

// ---------- kernel 0a: e_sq, zero accumulators ----------
__global__ __launch_bounds__(256) void k0a_prep(const float* __restrict__ cb,
                                                float* __restrict__ ws, int ntab) {
  int k = blockIdx.x, c = threadIdx.x;
  float v = cb[k * C_DIM + c];
  for (int t = 0; t < ntab; ++t)
    ws[WS_ACC + (size_t)t * (K_NUM * C_DIM) + k * C_DIM + c] = 0.f;
  float s = v * v;
  #pragma unroll
  for (int o = 32; o > 0; o >>= 1) s += __shfl_down(s, o, 64);
  __shared__ float ls[4];
  if ((c & 63) == 0) ls[c >> 6] = s;
  __syncthreads();
  if (c == 0) {
    ws[WS_ESQ + k] = ls[0] + ls[1] + ls[2] + ls[3];
    ws[WS_CNT + k] = 0.f;
    if (k == 0) ws[WS_LOSS] = 0.f;
  }
}

// ---------- kernel 0b: codebook transpose [k][c] -> [c][k] (LDS-tiled) ----------
__global__ __launch_bounds__(256) void k0b_transpose(const float* __restrict__ cb,
                                                     float* __restrict__ cbT) {
  __shared__ float t[64 * 69];
  int tid = threadIdx.x;
  int k0 = (blockIdx.x >> 2) * 64;
  int c0 = (blockIdx.x & 3) * 64;
  {
    int kk = tid >> 4, cq = tid & 15;
    #pragma unroll
    for (int r = 0; r < 4; ++r) {
      int row = kk + 16 * r;
      float4 v = *(const float4*)&cb[(size_t)(k0 + row) * C_DIM + c0 + 4 * cq];
      float* p = &t[row * 69 + 4 * cq];
      p[0] = v.x; p[1] = v.y; p[2] = v.z; p[3] = v.w;
    }
  }
  __syncthreads();
  {
    int kq = tid & 15, cc = tid >> 4;
    #pragma unroll
    for (int r = 0; r < 4; ++r) {
      int c = cc + 16 * r;
      float4 v;
      v.x = t[(4 * kq + 0) * 69 + c];
      v.y = t[(4 * kq + 1) * 69 + c];
      v.z = t[(4 * kq + 2) * 69 + c];
      v.w = t[(4 * kq + 3) * 69 + c];
      *(float4*)&cbT[(size_t)(c0 + c) * K_NUM + k0 + 4 * kq] = v;
    }
  }
}

// ---------- k1: distance-GEMM + argmin + z_q write + loss (NO embed atomics) ----------
// grid 512 x 256. Block: 128 consecutive n (fixed b,d), all 512 k.
// Thread tile 8n x 8k (acc=64 floats -> fits 128-VGPR budget, no spill).
__global__ __launch_bounds__(256)
__attribute__((amdgpu_waves_per_eu(2, 4)))
void k1_gemm(const float* __restrict__ z,
             const float* __restrict__ cb,
             float* __restrict__ out,
             float* __restrict__ ws) {
  __shared__ __align__(16) float zt[32 * 132];   // z tile [cc][n], pad 132 (16.9 KB)
  __shared__ __align__(16) float ct[32 * 128];   // code tile [cc][k]       (16 KB)
  __shared__ __align__(16) int   s_fidx[128];
  __shared__ float s_fmv[128];
  __shared__ float s_ls[4];

  const float* cbT = ws + WS_CBT;
  const float* esq = ws + WS_ESQ;

  int tid = threadIdx.x;
  int nb = blockIdx.x << 7;          // n base
  int b = nb >> 12;
  int d = (nb >> 8) & 15;
  int off = nb & 255;
  size_t base = (size_t)b * 1048576 + (size_t)d * 256 + off;  // + c*4096 + j
  const float* zbase = z + base;

  int wn = tid >> 4;   // [0,16): 8-n group (float4 at 4*wn and 64+4*wn)
  int wk = tid & 15;   // [0,16): 8-k group (float4 at 4*wk and 64+4*wk)

  float minv[8]; int mini[8];
  #pragma unroll
  for (int i = 0; i < 8; ++i) { minv[i] = FLT_MAX; mini[i] = 0; }

  for (int kc = 0; kc < 4; ++kc) {   // 4 k-chunks of 128
    float acc[8][8];
    #pragma unroll
    for (int i = 0; i < 8; ++i)
      #pragma unroll
      for (int j = 0; j < 8; ++j) acc[i][j] = 0.f;

    for (int c4 = 0; c4 < 8; ++c4) { // 8 c-chunks of 32
      int c0 = c4 * 32;
      __syncthreads();
      // stage z tile: 32 rows x 128 n = 1024 float4, 4 per thread
      #pragma unroll
      for (int r = 0; r < 4; ++r) {
        int idx4 = tid + 256 * r;
        int cc = idx4 >> 5, j4 = idx4 & 31;
        float4 v = *(const float4*)(zbase + (size_t)(c0 + cc) * 4096 + 4 * j4);
        *(float4*)&zt[cc * 132 + 4 * j4] = v;
      }
      // stage code tile: 32 rows x 128 k = 1024 float4, 4 per thread
      #pragma unroll
      for (int r = 0; r < 4; ++r) {
        int idx4 = tid + 256 * r;
        int cc = idx4 >> 5, k4 = idx4 & 31;
        float4 v = *(const float4*)(cbT + (size_t)(c0 + cc) * K_NUM + kc * 128 + 4 * k4);
        *(float4*)&ct[cc * 128 + 4 * k4] = v;
      }
      __syncthreads();
      #pragma unroll 4
      for (int cc = 0; cc < 32; ++cc) {
        float4 za = *(const float4*)&zt[cc * 132 + 4 * wn];        // 4-addr broadcast
        float4 zb = *(const float4*)&zt[cc * 132 + 64 + 4 * wn];
        float4 ca = *(const float4*)&ct[cc * 128 + 4 * wk];        // 2-way alias: free
        float4 cb4 = *(const float4*)&ct[cc * 128 + 64 + 4 * wk];
        float zr[8] = {za.x, za.y, za.z, za.w, zb.x, zb.y, zb.z, zb.w};
        float cr[8] = {ca.x, ca.y, ca.z, ca.w, cb4.x, cb4.y, cb4.z, cb4.w};
        #pragma unroll
        for (int i = 0; i < 8; ++i)
          #pragma unroll
          for (int j = 0; j < 8; ++j) acc[i][j] += zr[i] * cr[j];
      }
    }
    // running lexicographic min with val = e^2 - 2*dot (z^2 is a per-n shift)
    #pragma unroll
    for (int j = 0; j < 8; ++j) {
      int kg = kc * 128 + (j >> 2) * 64 + 4 * wk + (j & 3);
      float er = esq[kg];
      #pragma unroll
      for (int i = 0; i < 8; ++i) {
        float val = er - 2.f * acc[i][j];
        if (val < minv[i] || (val == minv[i] && kg < mini[i])) { minv[i] = val; mini[i] = kg; }
      }
    }
  }
  // in-register argmin reduce across the 16 wk lanes (lex butterfly, width 16)
  #pragma unroll
  for (int i = 0; i < 8; ++i) {
    float v = minv[i]; int ii = mini[i];
    #pragma unroll
    for (int o = 8; o > 0; o >>= 1) {
      float ov = __shfl_xor(v, o, 16);
      int   oi = __shfl_xor(ii, o, 16);
      if (ov < v || (ov == v && oi < ii)) { v = ov; ii = oi; }
    }
    if (wk == i) {
      int n = (i >> 2) * 64 + 4 * wn + (i & 3);
      s_fidx[n] = ii; s_fmv[n] = v;
      out[OFF_IDX + nb + n] = (float)ii;
    }
  }
  __syncthreads();
  // z_q gather-write + z^2 for loss — float4 over n (NO atomics here)
  int j4 = (tid & 31) * 4;   // n offset
  int ch = tid >> 5;         // c residue 0..7
  int4 idxs = *(const int4*)&s_fidx[j4];
  const float* r0 = cb + (size_t)idxs.x * C_DIM;
  const float* r1 = cb + (size_t)idxs.y * C_DIM;
  const float* r2 = cb + (size_t)idxs.z * C_DIM;
  const float* r3 = cb + (size_t)idxs.w * C_DIM;
  float zsq = 0.f;
  #pragma unroll 4
  for (int i = 0; i < 32; ++i) {
    int c = ch + 8 * i;
    float4 zv = *(const float4*)(zbase + (size_t)c * 4096 + j4);
    float4 q = make_float4(r0[c], r1[c], r2[c], r3[c]);
    *(float4*)(out + base + (size_t)c * 4096 + j4) = q;
    zsq += zv.x * zv.x + zv.y * zv.y + zv.z * zv.z + zv.w * zv.w;
  }
  if (tid < 128) zsq += s_fmv[tid];   // ||z-e||^2 = z^2 + (e^2 - 2 dot)
  #pragma unroll
  for (int o = 32; o > 0; o >>= 1) zsq += __shfl_down(zsq, o, 64);
  if ((tid & 63) == 0) s_ls[tid >> 6] = zsq;
  __syncthreads();
  if (tid == 0) unsafeAtomicAdd(&ws[WS_LOSS], s_ls[0] + s_ls[1] + s_ls[2] + s_ls[3]);
}

// ---------- k1b: embed-sum + counts scatter (ALL the atomics, isolated) ----------
// grid 512 x 256. Block: 128 consecutive n; reads indices back from out.
__global__ __launch_bounds__(256) void k1b_scatter(const float* __restrict__ z,
                                                   const float* __restrict__ out,
                                                   float* __restrict__ ws, int tabmask) {
  __shared__ __align__(16) int s_idx[128];
  float* accumE = ws + WS_ACC + (size_t)(blockIdx.x & tabmask) * (K_NUM * C_DIM);
  float* counts = ws + WS_CNT;

  int tid = threadIdx.x;
  int nb = blockIdx.x << 7;
  int b = nb >> 12;
  int d = (nb >> 8) & 15;
  int off = nb & 255;
  size_t base = (size_t)b * 1048576 + (size_t)d * 256 + off;
  const float* zbase = z + base;

  if (tid < 128) {
    int ii = (int)out[OFF_IDX + nb + tid];
    s_idx[tid] = ii;
    unsafeAtomicAdd(&counts[ii], 1.f);
  }
  __syncthreads();

  int j4 = (tid & 31) * 4;
  int ch = tid >> 5;
  int4 idxs = *(const int4*)&s_idx[j4];
  #pragma unroll 4
  for (int i = 0; i < 32; ++i) {
    int c = ch + 8 * i;
    float4 zv = *(const float4*)(zbase + (size_t)c * 4096 + j4);
    unsafeAtomicAdd(&accumE[idxs.x * C_DIM + c], zv.x);
    unsafeAtomicAdd(&accumE[idxs.y * C_DIM + c], zv.y);
    unsafeAtomicAdd(&accumE[idxs.z * C_DIM + c], zv.z);
    unsafeAtomicAdd(&accumE[idxs.w * C_DIM + c], zv.w);
  }
}

// ---------- kernel 2: cluster-size EMA + smoothing + loss scalar ----------
__global__ __launch_bounds__(512) void k2_cluster(const float* __restrict__ ema_cs,
                                                  float* __restrict__ out,
                                                  float* __restrict__ ws) {
  int k = threadIdx.x;
  float ncs = 0.99f * ema_cs[k] + 0.01f * ws[WS_CNT + k];
  out[OFF_CS + k] = ncs;
  float s = ncs;
  #pragma unroll
  for (int o = 32; o > 0; o >>= 1) s += __shfl_down(s, o, 64);
  __shared__ float ls[8];
  __shared__ float ntot;
  if ((k & 63) == 0) ls[k >> 6] = s;
  __syncthreads();
  if (k == 0) {
    float n = 0.f;
    #pragma unroll
    for (int i = 0; i < 8; ++i) n += ls[i];
    ntot = n;
    out[OFF_LOSS] = 0.5f * ws[WS_LOSS] / 16777216.f;
  }
  __syncthreads();
  float n = ntot;
  ws[WS_SMOOTH + k] = (ncs + 1e-5f) / (n + 0.00512f) * n;
}

// ---------- kernel 3: embed-sum EMA + normalized codebook (sums ntab tables) ----------
__global__ __launch_bounds__(256) void k3_embed(const float* __restrict__ ema_es,
                                                float* __restrict__ out,
                                                const float* __restrict__ ws, int ntab) {
  int k = blockIdx.x, c = threadIdx.x;
  int i = k * C_DIM + c;
  float bs = 0.f;
  for (int t = 0; t < ntab; ++t) bs += ws[WS_ACC + (size_t)t * (K_NUM * C_DIM) + i];
  float es = 0.99f * ema_es[i] + 0.01f * bs;
  out[OFF_ES + i] = es;
  out[OFF_CB + i] = es / ws[WS_SMOOTH + k];
}

extern "C" void kernel_launch(void* const* d_in, const int* in_sizes, int n_in,
                              void* d_out, int out_size, void* d_ws, size_t ws_size,
                              hipStream_t stream) {
  const float* z      = (const float*)d_in[0];
  const float* cb     = (const float*)d_in[1];
  const float* ema_cs = (const float*)d_in[2];
  const float* ema_es = (const float*)d_in[3];
  float* out = (float*)d_out;
  float* ws  = (float*)d_ws;

  // pick replication factor that fits ws_size (defensive vs OOB)
  size_t avail = ws_size / 4;   // floats
  int ntab = MAXTAB;
  while (ntab > 1 && (size_t)WS_ACC + (size_t)ntab * (K_NUM * C_DIM) > avail) ntab >>= 1;
  int tabmask = ntab - 1;

  k0a_prep<<<512, 256, 0, stream>>>(cb, ws, ntab);
  k0b_transpose<<<32, 256, 0, stream>>>(cb, ws + WS_CBT);
  k1_gemm<<<512, 256, 0, stream>>>(z, cb, out, ws);
  k1b_scatter<<<512, 256, 0, stream>>>(z, out, ws, tabmask);
  k2_cluster<<<1, 512, 0, stream>>>(ema_cs, out, ws);
  k3_embed<<<512, 256, 0, stream>>>(ema_es, out, ws, ntab);
}

// Round 8
// 663.022 us; speedup vs baseline: 1.9585x; 1.9585x over previous
//
#include <hip/hip_runtime.h>
#include <cfloat>

#define K_NUM 512
#define C_DIM 256

// workspace float offsets — small fixed region first, private tables last
#define WS_CNT    0          // [512] cluster counts
#define WS_ESQ    512        // [512] ||e_k||^2
#define WS_SMOOTH 1024       // [512] smoothed cluster size
#define WS_LOSS   1536       // [1] (+pad)
#define WS_CBT    2048       // [256][512] transposed codebook
#define WS_ACC    133120     // nblk x [512][256] private embed-sum tables

// output float offsets (z_q, vq_loss, indices, new_codebook, new_cluster_size, new_embed_sum)
#define OFF_LOSS 16777216
#define OFF_IDX  16777217
#define OFF_CB   16842753
#define OFF_CS   16973825
#define OFF_ES   16974337

// ---------- kernel 0a: e_sq + zero counts/loss ----------
__global__ __launch_bounds__(256) void k0a_prep(const float* __restrict__ cb,
                                                float* __restrict__ ws) {
  int k = blockIdx.x, c = threadIdx.x;
  float v = cb[k * C_DIM + c];
  float s = v * v;
  #pragma unroll
  for (int o = 32; o > 0; o >>= 1) s += __shfl_down(s, o, 64);
  __shared__ float ls[4];
  if ((c & 63) == 0) ls[c >> 6] = s;
  __syncthreads();
  if (c == 0) {
    ws[WS_ESQ + k] = ls[0] + ls[1] + ls[2] + ls[3];
    ws[WS_CNT + k] = 0.f;
    if (k == 0) ws[WS_LOSS] = 0.f;
  }
}

// ---------- kernel 0b: codebook transpose [k][c] -> [c][k] (LDS-tiled) ----------
__global__ __launch_bounds__(256) void k0b_transpose(const float* __restrict__ cb,
                                                     float* __restrict__ cbT) {
  __shared__ float t[64 * 69];
  int tid = threadIdx.x;
  int k0 = (blockIdx.x >> 2) * 64;
  int c0 = (blockIdx.x & 3) * 64;
  {
    int kk = tid >> 4, cq = tid & 15;
    #pragma unroll
    for (int r = 0; r < 4; ++r) {
      int row = kk + 16 * r;
      float4 v = *(const float4*)&cb[(size_t)(k0 + row) * C_DIM + c0 + 4 * cq];
      float* p = &t[row * 69 + 4 * cq];
      p[0] = v.x; p[1] = v.y; p[2] = v.z; p[3] = v.w;
    }
  }
  __syncthreads();
  {
    int kq = tid & 15, cc = tid >> 4;
    #pragma unroll
    for (int r = 0; r < 4; ++r) {
      int c = cc + 16 * r;
      float4 v;
      v.x = t[(4 * kq + 0) * 69 + c];
      v.y = t[(4 * kq + 1) * 69 + c];
      v.z = t[(4 * kq + 2) * 69 + c];
      v.w = t[(4 * kq + 3) * 69 + c];
      *(float4*)&cbT[(size_t)(c0 + c) * K_NUM + k0 + 4 * kq] = v;
    }
  }
}

// ---------- k1: distance-GEMM + argmin + z_q write + loss (NO embed atomics) ----------
// grid 512 x 256. Block: 128 consecutive n (fixed b,d), all 512 k.
// Thread tile 8n x 8k (acc=64 floats -> fits 128-VGPR budget, no spill).
__global__ __launch_bounds__(256)
__attribute__((amdgpu_waves_per_eu(2, 4)))
void k1_gemm(const float* __restrict__ z,
             const float* __restrict__ cb,
             float* __restrict__ out,
             float* __restrict__ ws) {
  __shared__ __align__(16) float zt[32 * 132];   // z tile [cc][n], pad 132 (16.9 KB)
  __shared__ __align__(16) float ct[32 * 128];   // code tile [cc][k]       (16 KB)
  __shared__ __align__(16) int   s_fidx[128];
  __shared__ float s_fmv[128];
  __shared__ float s_ls[4];

  const float* cbT = ws + WS_CBT;
  const float* esq = ws + WS_ESQ;

  int tid = threadIdx.x;
  int nb = blockIdx.x << 7;          // n base
  int b = nb >> 12;
  int d = (nb >> 8) & 15;
  int off = nb & 255;
  size_t base = (size_t)b * 1048576 + (size_t)d * 256 + off;  // + c*4096 + j
  const float* zbase = z + base;

  int wn = tid >> 4;   // [0,16): 8-n group (float4 at 4*wn and 64+4*wn)
  int wk = tid & 15;   // [0,16): 8-k group (float4 at 4*wk and 64+4*wk)

  float minv[8]; int mini[8];
  #pragma unroll
  for (int i = 0; i < 8; ++i) { minv[i] = FLT_MAX; mini[i] = 0; }

  for (int kc = 0; kc < 4; ++kc) {   // 4 k-chunks of 128
    float acc[8][8];
    #pragma unroll
    for (int i = 0; i < 8; ++i)
      #pragma unroll
      for (int j = 0; j < 8; ++j) acc[i][j] = 0.f;

    for (int c4 = 0; c4 < 8; ++c4) { // 8 c-chunks of 32
      int c0 = c4 * 32;
      __syncthreads();
      #pragma unroll
      for (int r = 0; r < 4; ++r) {
        int idx4 = tid + 256 * r;
        int cc = idx4 >> 5, j4 = idx4 & 31;
        float4 v = *(const float4*)(zbase + (size_t)(c0 + cc) * 4096 + 4 * j4);
        *(float4*)&zt[cc * 132 + 4 * j4] = v;
      }
      #pragma unroll
      for (int r = 0; r < 4; ++r) {
        int idx4 = tid + 256 * r;
        int cc = idx4 >> 5, k4 = idx4 & 31;
        float4 v = *(const float4*)(cbT + (size_t)(c0 + cc) * K_NUM + kc * 128 + 4 * k4);
        *(float4*)&ct[cc * 128 + 4 * k4] = v;
      }
      __syncthreads();
      #pragma unroll 4
      for (int cc = 0; cc < 32; ++cc) {
        float4 za = *(const float4*)&zt[cc * 132 + 4 * wn];        // 4-addr broadcast
        float4 zb = *(const float4*)&zt[cc * 132 + 64 + 4 * wn];
        float4 ca = *(const float4*)&ct[cc * 128 + 4 * wk];        // 2-way alias: free
        float4 cb4 = *(const float4*)&ct[cc * 128 + 64 + 4 * wk];
        float zr[8] = {za.x, za.y, za.z, za.w, zb.x, zb.y, zb.z, zb.w};
        float cr[8] = {ca.x, ca.y, ca.z, ca.w, cb4.x, cb4.y, cb4.z, cb4.w};
        #pragma unroll
        for (int i = 0; i < 8; ++i)
          #pragma unroll
          for (int j = 0; j < 8; ++j) acc[i][j] += zr[i] * cr[j];
      }
    }
    #pragma unroll
    for (int j = 0; j < 8; ++j) {
      int kg = kc * 128 + (j >> 2) * 64 + 4 * wk + (j & 3);
      float er = esq[kg];
      #pragma unroll
      for (int i = 0; i < 8; ++i) {
        float val = er - 2.f * acc[i][j];
        if (val < minv[i] || (val == minv[i] && kg < mini[i])) { minv[i] = val; mini[i] = kg; }
      }
    }
  }
  // in-register argmin reduce across the 16 wk lanes (lex butterfly, width 16)
  #pragma unroll
  for (int i = 0; i < 8; ++i) {
    float v = minv[i]; int ii = mini[i];
    #pragma unroll
    for (int o = 8; o > 0; o >>= 1) {
      float ov = __shfl_xor(v, o, 16);
      int   oi = __shfl_xor(ii, o, 16);
      if (ov < v || (ov == v && oi < ii)) { v = ov; ii = oi; }
    }
    if (wk == i) {
      int n = (i >> 2) * 64 + 4 * wn + (i & 3);
      s_fidx[n] = ii; s_fmv[n] = v;
      out[OFF_IDX + nb + n] = (float)ii;
    }
  }
  __syncthreads();
  // z_q gather-write + z^2 for loss — float4 over n (NO atomics here)
  int j4 = (tid & 31) * 4;   // n offset
  int ch = tid >> 5;         // c residue 0..7
  int4 idxs = *(const int4*)&s_fidx[j4];
  const float* r0 = cb + (size_t)idxs.x * C_DIM;
  const float* r1 = cb + (size_t)idxs.y * C_DIM;
  const float* r2 = cb + (size_t)idxs.z * C_DIM;
  const float* r3 = cb + (size_t)idxs.w * C_DIM;
  float zsq = 0.f;
  #pragma unroll 4
  for (int i = 0; i < 32; ++i) {
    int c = ch + 8 * i;
    float4 zv = *(const float4*)(zbase + (size_t)c * 4096 + j4);
    float4 q = make_float4(r0[c], r1[c], r2[c], r3[c]);
    *(float4*)(out + base + (size_t)c * 4096 + j4) = q;
    zsq += zv.x * zv.x + zv.y * zv.y + zv.z * zv.z + zv.w * zv.w;
  }
  if (tid < 128) zsq += s_fmv[tid];   // ||z-e||^2 = z^2 + (e^2 - 2 dot)
  #pragma unroll
  for (int o = 32; o > 0; o >>= 1) zsq += __shfl_down(zsq, o, 64);
  if ((tid & 63) == 0) s_ls[tid >> 6] = zsq;
  __syncthreads();
  if (tid == 0) unsafeAtomicAdd(&ws[WS_LOSS], s_ls[0] + s_ls[1] + s_ls[2] + s_ls[3]);
}

// ---------- k1b: embed-sum via LDS-accumulated PRIVATE tables (atomic-free flush) ----------
// grid nblk x 256. Block owns n_per consecutive n; LDS table [512][65] covers one
// c-quarter per pass (4 passes). z read once total; flush = plain stores.
__global__ __launch_bounds__(256) void k1b_scatter(const float* __restrict__ z,
                                                   const float* __restrict__ out,
                                                   float* __restrict__ ws, int n_per) {
  __shared__ float tab[K_NUM * 65];   // 133,120 B -> 1 block/CU
  float* counts = ws + WS_CNT;
  float* myTab = ws + WS_ACC + (size_t)blockIdx.x * (K_NUM * C_DIM);

  int tid = threadIdx.x;
  int nb = blockIdx.x * n_per;

  for (int pass = 0; pass < 4; ++pass) {
    int cq = pass * 64;
    for (int i = tid; i < K_NUM * 65; i += 256) tab[i] = 0.f;
    __syncthreads();

    for (int nn = tid * 4; nn < n_per; nn += 1024) {
      int n0 = nb + nn;
      // scalar index loads (OFF_IDX base is only 4B-aligned — no dwordx4 here)
      int i0 = (int)out[OFF_IDX + n0 + 0];
      int i1 = (int)out[OFF_IDX + n0 + 1];
      int i2 = (int)out[OFF_IDX + n0 + 2];
      int i3 = (int)out[OFF_IDX + n0 + 3];
      if (pass == 0) {
        unsafeAtomicAdd(&counts[i0], 1.f);
        unsafeAtomicAdd(&counts[i1], 1.f);
        unsafeAtomicAdd(&counts[i2], 1.f);
        unsafeAtomicAdd(&counts[i3], 1.f);
      }
      int a0 = i0 * 65, a1 = i1 * 65, a2 = i2 * 65, a3 = i3 * 65;
      // n0..n0+3 lie in one b-plane (n0 multiple of 4; planes are 4096-aligned)
      size_t basez = (size_t)(n0 >> 12) * 1048576 + (size_t)(n0 & 4095);
      const float* zp = z + basez + (size_t)cq * 4096;
      #pragma unroll 8
      for (int cl = 0; cl < 64; ++cl) {
        float4 zv = *(const float4*)(zp + (size_t)cl * 4096);
        atomicAdd(&tab[a0 + cl], zv.x);   // ds_add_f32, bank = (k+c)&31 — spread
        atomicAdd(&tab[a1 + cl], zv.y);
        atomicAdd(&tab[a2 + cl], zv.z);
        atomicAdd(&tab[a3 + cl], zv.w);
      }
    }
    __syncthreads();
    // flush c-quarter to private global table: plain coalesced stores
    int cl = tid & 63, kr = tid >> 6;
    for (int k0 = 0; k0 < K_NUM; k0 += 4) {
      int k = k0 + kr;
      myTab[k * C_DIM + cq + cl] = tab[k * 65 + cl];
    }
    __syncthreads();
  }
}

// ---------- kernel 2: cluster-size EMA + smoothing + loss scalar ----------
__global__ __launch_bounds__(512) void k2_cluster(const float* __restrict__ ema_cs,
                                                  float* __restrict__ out,
                                                  float* __restrict__ ws) {
  int k = threadIdx.x;
  float ncs = 0.99f * ema_cs[k] + 0.01f * ws[WS_CNT + k];
  out[OFF_CS + k] = ncs;
  float s = ncs;
  #pragma unroll
  for (int o = 32; o > 0; o >>= 1) s += __shfl_down(s, o, 64);
  __shared__ float ls[8];
  __shared__ float ntot;
  if ((k & 63) == 0) ls[k >> 6] = s;
  __syncthreads();
  if (k == 0) {
    float n = 0.f;
    #pragma unroll
    for (int i = 0; i < 8; ++i) n += ls[i];
    ntot = n;
    out[OFF_LOSS] = 0.5f * ws[WS_LOSS] / 16777216.f;
  }
  __syncthreads();
  float n = ntot;
  ws[WS_SMOOTH + k] = (ncs + 1e-5f) / (n + 0.00512f) * n;
}

// ---------- kernel 3: embed-sum EMA + normalized codebook (sums nblk tables) ----------
__global__ __launch_bounds__(256) void k3_embed(const float* __restrict__ ema_es,
                                                float* __restrict__ out,
                                                const float* __restrict__ ws, int nblk) {
  int k = blockIdx.x, c = threadIdx.x;
  int i = k * C_DIM + c;
  float bs = 0.f;
  for (int t = 0; t < nblk; ++t) bs += ws[WS_ACC + (size_t)t * (K_NUM * C_DIM) + i];
  float es = 0.99f * ema_es[i] + 0.01f * bs;
  out[OFF_ES + i] = es;
  out[OFF_CB + i] = es / ws[WS_SMOOTH + k];
}

extern "C" void kernel_launch(void* const* d_in, const int* in_sizes, int n_in,
                              void* d_out, int out_size, void* d_ws, size_t ws_size,
                              hipStream_t stream) {
  const float* z      = (const float*)d_in[0];
  const float* cb     = (const float*)d_in[1];
  const float* ema_cs = (const float*)d_in[2];
  const float* ema_es = (const float*)d_in[3];
  float* out = (float*)d_out;
  float* ws  = (float*)d_ws;

  // private-table count: as many as ws allows, up to 128 (ws-adaptive, no OOB)
  size_t avail = ws_size / 4;   // floats
  int nblk = 128;
  while (nblk > 8 && (size_t)WS_ACC + (size_t)nblk * (K_NUM * C_DIM) > avail) nblk >>= 1;
  int n_per = 65536 / nblk;

  k0a_prep<<<512, 256, 0, stream>>>(cb, ws);
  k0b_transpose<<<32, 256, 0, stream>>>(cb, ws + WS_CBT);
  k1_gemm<<<512, 256, 0, stream>>>(z, cb, out, ws);
  k1b_scatter<<<nblk, 256, 0, stream>>>(z, out, ws, n_per);
  k2_cluster<<<1, 512, 0, stream>>>(ema_cs, out, ws);
  k3_embed<<<512, 256, 0, stream>>>(ema_es, out, ws, nblk);
}